// Round 6
// baseline (107.816 us; speedup 1.0000x reference)
//
#include <hip/hip_runtime.h>

#define NN 512
#define NE 16384
#define NF 64

typedef __attribute__((ext_vector_type(8))) short short8_t;
typedef __attribute__((ext_vector_type(4))) float float4_t;

__device__ inline unsigned short f2bf(float f) {
  unsigned u = __builtin_bit_cast(unsigned, f);
  u += 0x7fff + ((u >> 16) & 1);  // round-to-nearest-even (finite inputs)
  return (unsigned short)(u >> 16);
}
__device__ inline float bf2f(unsigned short u) {
  unsigned v = ((unsigned)u) << 16;
  return __builtin_bit_cast(float, v);
}

// ---------------------------------------------------------------------------
// K1: clear presence bitmasks (64 KB) + convert W_mlp1/W_mlp2 to bf16.
// Grid: 128 x 256 = 32768 threads.
// ---------------------------------------------------------------------------
__global__ __launch_bounds__(256) void k_init(const float* __restrict__ Wm1,
                                              const float* __restrict__ Wm2,
                                              unsigned* __restrict__ masks,  // 16384 dw
                                              unsigned short* __restrict__ W1B,
                                              unsigned short* __restrict__ W2B) {
  int t = blockIdx.x * 256 + threadIdx.x;
  if (t < 16384) {
    masks[t] = 0u;
    float4 v = ((const float4*)Wm1)[t];
    short4 s;
    s.x = f2bf(v.x); s.y = f2bf(v.y); s.z = f2bf(v.z); s.w = f2bf(v.w);
    ((short4*)W1B)[t] = s;
  } else if (t < 24576) {
    int i = t - 16384;
    float4 v = ((const float4*)Wm2)[i];
    short4 s;
    s.x = f2bf(v.x); s.y = f2bf(v.y); s.z = f2bf(v.z); s.w = f2bf(v.w);
    ((short4*)W2B)[i] = s;
  }
}

// ---------------------------------------------------------------------------
// K2: X = C@W_L1^T, Y = C@W_L2^T via bf16 MFMA (bf16 out), fused with the
// edge scatter (ids + presence bits). Block = 4 waves x 16 edges.
// ---------------------------------------------------------------------------
__global__ __launch_bounds__(256) void k_xy_mfma(const float* __restrict__ C,
                                                 const float* __restrict__ W1,
                                                 const float* __restrict__ W2,
                                                 const int* __restrict__ ei,
                                                 int* __restrict__ eid,
                                                 int* __restrict__ eidT,
                                                 unsigned* __restrict__ maskO,
                                                 unsigned* __restrict__ maskI,
                                                 unsigned short* __restrict__ Xb,
                                                 unsigned short* __restrict__ Yb) {
  __shared__ __attribute__((aligned(16))) short W1s[64 * 72];
  __shared__ __attribute__((aligned(16))) short W2s[64 * 72];
  int t = threadIdx.x;
  int w = t >> 6;
  int lane = t & 63;
  int col = lane & 15;
  int q = lane >> 4;
  int base_e = blockIdx.x * 64 + w * 16;

  // scatter this block's 64 edges: id tables + presence bits
  if (t < 64) {
    int e = blockIdx.x * 64 + t;
    int i = ei[e];
    int k = ei[NE + e];
    eid[i * NN + k] = e;
    eidT[k * NN + i] = e;
    atomicOr(&maskO[i * 16 + (k >> 5)], 1u << (k & 31));
    atomicOr(&maskI[k * 16 + (i >> 5)], 1u << (i & 31));
  }

  // stage W1,W2 (fp32 global -> bf16 LDS), 64 rows x 16 float4 granules
#pragma unroll
  for (int z = 0; z < 4; z++) {
    int gi = z * 256 + t;
    int r = gi >> 4, c = gi & 15;
    float4 v1 = ((const float4*)W1)[r * 16 + c];
    float4 v2 = ((const float4*)W2)[r * 16 + c];
    short4 s1, s2;
    s1.x = f2bf(v1.x); s1.y = f2bf(v1.y); s1.z = f2bf(v1.z); s1.w = f2bf(v1.w);
    s2.x = f2bf(v2.x); s2.y = f2bf(v2.y); s2.z = f2bf(v2.z); s2.w = f2bf(v2.w);
    *(short4*)(W1s + r * 72 + c * 4) = s1;
    *(short4*)(W2s + r * 72 + c * 4) = s2;
  }
  __syncthreads();

  // load C rows (fp32), convert to B-fragments
  short8_t bfrag[2];
#pragma unroll
  for (int ks = 0; ks < 2; ks++) {
    float4 c0 = ((const float4*)C)[(size_t)(base_e + col) * 16 + ks * 8 + q * 2];
    float4 c1 = ((const float4*)C)[(size_t)(base_e + col) * 16 + ks * 8 + q * 2 + 1];
    short8_t s;
    s[0] = (short)f2bf(c0.x); s[1] = (short)f2bf(c0.y);
    s[2] = (short)f2bf(c0.z); s[3] = (short)f2bf(c0.w);
    s[4] = (short)f2bf(c1.x); s[5] = (short)f2bf(c1.y);
    s[6] = (short)f2bf(c1.z); s[7] = (short)f2bf(c1.w);
    bfrag[ks] = s;
  }

  float4_t xa[4], ya[4];
#pragma unroll
  for (int ft = 0; ft < 4; ft++) {
    xa[ft] = (float4_t){0.f, 0.f, 0.f, 0.f};
    ya[ft] = (float4_t){0.f, 0.f, 0.f, 0.f};
  }
#pragma unroll
  for (int ks = 0; ks < 2; ks++) {
#pragma unroll
    for (int ft = 0; ft < 4; ft++) {
      short8_t a1 = *(const short8_t*)(W1s + (ft * 16 + col) * 72 + ks * 32 + q * 8);
      short8_t a2 = *(const short8_t*)(W2s + (ft * 16 + col) * 72 + ks * 32 + q * 8);
      xa[ft] = __builtin_amdgcn_mfma_f32_16x16x32_bf16(a1, bfrag[ks], xa[ft], 0, 0, 0);
      ya[ft] = __builtin_amdgcn_mfma_f32_16x16x32_bf16(a2, bfrag[ks], ya[ft], 0, 0, 0);
    }
  }
  // D[row=q*4+r -> f][col -> edge]; store bf16 short4
#pragma unroll
  for (int ft = 0; ft < 4; ft++) {
    short4 sx, sy;
    sx.x = (short)f2bf(xa[ft][0]); sx.y = (short)f2bf(xa[ft][1]);
    sx.z = (short)f2bf(xa[ft][2]); sx.w = (short)f2bf(xa[ft][3]);
    sy.x = (short)f2bf(ya[ft][0]); sy.y = (short)f2bf(ya[ft][1]);
    sy.z = (short)f2bf(ya[ft][2]); sy.w = (short)f2bf(ya[ft][3]);
    *(short4*)(Xb + (size_t)(base_e + col) * 64 + ft * 16 + q * 4) = sx;
    *(short4*)(Yb + (size_t)(base_e + col) * 64 + ft * 16 + q * 4) = sy;
  }
}

// ---------------------------------------------------------------------------
// K3: fused sparse-product + MLP.
// Block = 4 waves, 32 edges, grid 512 -> 2 blocks/CU, 8 waves/CU.
// Phase 0 (spmm): each wave computes TM for 8 of the block's edges via bitmask
//   intersection (masks prefetched for all 8 edges; ~2 matches/edge; gather
//   bf16 X/Y rows; wave-wide FMA, lane = feature) -> LDS tmpS (aliases hS).
// Phase 1: build B-fragments of [C | TM]: C half direct from global fp32
//   (convert in flight), TM half from tmpS via ds_read_b128.
// Phase 2: the R3 hidden-split MLP loop (2 edge-groups x 2 hidden-halves),
//   cross-half reduction through LDS at the end.
// ---------------------------------------------------------------------------
__global__ __launch_bounds__(256) void k_smlp(
    const float* __restrict__ C,              // [NE][64] fp32
    const int* __restrict__ ei,
    const int* __restrict__ eid,
    const int* __restrict__ eidT,
    const unsigned* __restrict__ maskO,
    const unsigned* __restrict__ maskI,
    const unsigned short* __restrict__ Xb,    // [NE][64] bf16
    const unsigned short* __restrict__ Yb,
    const unsigned short* __restrict__ W1B,   // [512][128] bf16
    const unsigned short* __restrict__ W2B,   // [64][512] bf16
    float* __restrict__ out) {                // [NE][64]
  __shared__ __attribute__((aligned(16))) short W1s[128 * 136];  // 34816 B
  __shared__ __attribute__((aligned(16))) short W2s[64 * 136];   // 17408 B
  __shared__ __attribute__((aligned(16))) short hS[4][16 * 72];  //  9216 B

  int t = threadIdx.x;
  int w = t >> 6;
  int lane = t & 63;
  int col = lane & 15;
  int q = lane >> 4;
  int g = w & 1;
  int h = w >> 1;
  int base = blockIdx.x * 32;
  int base_e = base + g * 16;

  // ---- phase 0: spmm for this wave's 8 edges -> tmpS (alias of hS) ----
  short* tmpS = (short*)hS;  // [32 edges][72 shorts]
  {
    int iv[8], kv[8];
    unsigned mm[8];
#pragma unroll
    for (int n = 0; n < 8; n++) {
      int e = base + w * 8 + n;
      iv[n] = ei[e];
      kv[n] = ei[NE + e];
    }
#pragma unroll
    for (int n = 0; n < 8; n++)
      mm[n] = (lane < 16) ? (maskO[iv[n] * 16 + lane] & maskI[kv[n] * 16 + lane]) : 0u;
#pragma unroll
    for (int n = 0; n < 8; n++) {
      unsigned long long has = __ballot(mm[n] != 0);
      float acc = 0.f;
      while (has) {
        int l = (int)__builtin_ctzll(has);
        has &= has - 1;
        unsigned bits = __shfl(mm[n], l);
        while (bits) {
          int b = __builtin_ctz(bits);
          bits &= bits - 1;
          int j = l * 32 + b;
          int s1 = eid[iv[n] * NN + j];   // uniform -> broadcast load
          int s2 = eidT[kv[n] * NN + j];
          acc = fmaf(bf2f(Xb[(size_t)s1 * 64 + lane]),
                     bf2f(Yb[(size_t)s2 * 64 + lane]), acc);
        }
      }
      tmpS[(w * 8 + n) * 72 + lane] = (short)f2bf(acc);
    }
  }
  __syncthreads();

  // ---- phase 1: B-fragments of [C | TM] for edge group g ----
  short8_t btmp[4];
#pragma unroll
  for (int ks = 0; ks < 2; ks++) {  // C half: global fp32 -> bf16
    float4 c0 = ((const float4*)C)[(size_t)(base_e + col) * 16 + ks * 8 + q * 2];
    float4 c1 = ((const float4*)C)[(size_t)(base_e + col) * 16 + ks * 8 + q * 2 + 1];
    short8_t s;
    s[0] = (short)f2bf(c0.x); s[1] = (short)f2bf(c0.y);
    s[2] = (short)f2bf(c0.z); s[3] = (short)f2bf(c0.w);
    s[4] = (short)f2bf(c1.x); s[5] = (short)f2bf(c1.y);
    s[6] = (short)f2bf(c1.z); s[7] = (short)f2bf(c1.w);
    btmp[ks] = s;
  }
#pragma unroll
  for (int ks = 2; ks < 4; ks++)  // TM half: from tmpS
    btmp[ks] = *(const short8_t*)(tmpS + (g * 16 + col) * 72 + (ks - 2) * 32 + q * 8);

  float4_t oacc[4];
#pragma unroll
  for (int ft = 0; ft < 4; ft++) oacc[ft] = (float4_t){0.f, 0.f, 0.f, 0.f};

  // ---- phase 2: hidden-split MLP ----
  for (int it = 0; it < 4; it++) {
    __syncthreads();  // prev consumers done (it=0: btmp builds done -> hS safe)
    {  // stage W1 chunks (it) and (4+it): 128 rows x 16 uint4
      uint4* d1 = (uint4*)W1s;
      const uint4* s1 = (const uint4*)W1B;
#pragma unroll
      for (int z = 0; z < 8; z++) {
        int gi = z * 256 + t;
        int r = gi >> 4, c = gi & 15;
        int grow = ((r >> 6) * 4 + it) * 64 + (r & 63);
        d1[r * 17 + c] = s1[(size_t)grow * 16 + c];
      }
      uint4* d2 = (uint4*)W2s;
      const uint4* s2 = (const uint4*)W2B;
#pragma unroll
      for (int z = 0; z < 4; z++) {
        int gi = z * 256 + t;
        int r = gi >> 4, c = gi & 15;
        int gc = ((c >> 3) * 4 + it) * 8 + (c & 7);
        d2[r * 17 + c] = s2[(size_t)r * 64 + gc];
      }
    }
    __syncthreads();

    // GEMM1: hT[hid][edge] for this half's 64-hid chunk
#pragma unroll
    for (int ht = 0; ht < 4; ht++) {
      float4_t hacc = (float4_t){0.f, 0.f, 0.f, 0.f};
#pragma unroll
      for (int ks = 0; ks < 4; ks++) {
        short8_t af = *(const short8_t*)(W1s + (h * 64 + ht * 16 + col) * 136 + ks * 32 + q * 8);
        hacc = __builtin_amdgcn_mfma_f32_16x16x32_bf16(af, btmp[ks], hacc, 0, 0, 0);
      }
      short4 hp;  // regs r=0..3 -> hid ht*16+q*4+r, edge=col
      hp.x = (short)f2bf(fmaxf(hacc[0], 0.f));
      hp.y = (short)f2bf(fmaxf(hacc[1], 0.f));
      hp.z = (short)f2bf(fmaxf(hacc[2], 0.f));
      hp.w = (short)f2bf(fmaxf(hacc[3], 0.f));
      *(short4*)(&hS[w][col * 72 + ht * 16 + q * 4]) = hp;
    }
    // hS tile is per-wave: lgkmcnt-only hazard, no block barrier needed

    // GEMM2: oacc += relu(h) @ W2^T over this half's chunk
#pragma unroll
    for (int ks2 = 0; ks2 < 2; ks2++) {
      short8_t a2 = *(const short8_t*)(&hS[w][col * 72 + ks2 * 32 + q * 8]);
#pragma unroll
      for (int ft = 0; ft < 4; ft++) {
        short8_t b2 = *(const short8_t*)(W2s + (ft * 16 + col) * 136 + h * 64 + ks2 * 32 + q * 8);
        oacc[ft] = __builtin_amdgcn_mfma_f32_16x16x32_bf16(a2, b2, oacc[ft], 0, 0, 0);
      }
    }
  }

  // cross-half reduction via LDS, then store
  __syncthreads();
  float* red = (float*)W1s;  // [32 edges][stride 66] fp32
  if (h == 1) {
#pragma unroll
    for (int ft = 0; ft < 4; ft++)
#pragma unroll
      for (int r = 0; r < 4; r++)
        red[(g * 16 + q * 4 + r) * 66 + ft * 16 + col] = oacc[ft][r];
  }
  __syncthreads();
  if (h == 0) {
#pragma unroll
    for (int ft = 0; ft < 4; ft++)
#pragma unroll
      for (int r = 0; r < 4; r++) {
        float v = oacc[ft][r] + red[(g * 16 + q * 4 + r) * 66 + ft * 16 + col];
        out[(size_t)(base_e + q * 4 + r) * 64 + ft * 16 + col] = v;
      }
  }
}

// ---------------------------------------------------------------------------
extern "C" void kernel_launch(void* const* d_in, const int* in_sizes, int n_in,
                              void* d_out, int out_size, void* d_ws, size_t ws_size,
                              hipStream_t stream) {
  const int* ei = (const int*)d_in[0];       // [2, E]
  const float* C = (const float*)d_in[1];    // [E, 64]
  const float* W1 = (const float*)d_in[3];   // [64, 64]
  const float* W2 = (const float*)d_in[4];   // [64, 64]
  const float* Wm1 = (const float*)d_in[5];  // [512, 128]
  const float* Wm2 = (const float*)d_in[6];  // [64, 512]
  float* out = (float*)d_out;                // [E, 64]

  char* p = (char*)d_ws;
  int* eid = (int*)p;                 p += (size_t)NN * NN * 4;
  int* eidT = (int*)p;                p += (size_t)NN * NN * 4;
  unsigned* masks = (unsigned*)p;     p += (size_t)16384 * 4;  // maskO|maskI
  unsigned short* Xb = (unsigned short*)p;    p += (size_t)NE * NF * 2;
  unsigned short* Yb = (unsigned short*)p;    p += (size_t)NE * NF * 2;
  unsigned short* W1B = (unsigned short*)p;   p += (size_t)512 * 128 * 2;
  unsigned short* W2B = (unsigned short*)p;   p += (size_t)64 * 512 * 2;
  unsigned* maskO = masks;
  unsigned* maskI = masks + 8192;

  k_init<<<128, 256, 0, stream>>>(Wm1, Wm2, masks, W1B, W2B);
  k_xy_mfma<<<NE / 64, 256, 0, stream>>>(C, W1, W2, ei, eid, eidT, maskO, maskI, Xb, Yb);
  k_smlp<<<NE / 32, 256, 0, stream>>>(C, ei, eid, eidT, maskO, maskI, Xb, Yb, W1B, W2B, out);
}

// Round 7
// 97.468 us; speedup vs baseline: 1.1062x; 1.1062x over previous
//
#include <hip/hip_runtime.h>

#define NN 512
#define NE 16384
#define NF 64

typedef __attribute__((ext_vector_type(8))) short short8_t;
typedef __attribute__((ext_vector_type(4))) float float4_t;

__device__ inline unsigned short f2bf(float f) {
  unsigned u = __builtin_bit_cast(unsigned, f);
  u += 0x7fff + ((u >> 16) & 1);  // round-to-nearest-even (finite inputs)
  return (unsigned short)(u >> 16);
}
__device__ inline float bf2f(unsigned short u) {
  unsigned v = ((unsigned)u) << 16;
  return __builtin_bit_cast(float, v);
}

// ---------------------------------------------------------------------------
// K1: X = C@W_L1^T, Y = C@W_L2^T via bf16 MFMA (bf16 out), fused with the
// edge scatter (ids + presence bits). Block = 4 waves x 16 edges.
// Masks are pre-cleared by a hipMemsetAsync node (64 KB).
// ---------------------------------------------------------------------------
__global__ __launch_bounds__(256) void k_xy_mfma(const float* __restrict__ C,
                                                 const float* __restrict__ W1,
                                                 const float* __restrict__ W2,
                                                 const int* __restrict__ ei,
                                                 int* __restrict__ eid,
                                                 int* __restrict__ eidT,
                                                 unsigned* __restrict__ maskO,
                                                 unsigned* __restrict__ maskI,
                                                 unsigned short* __restrict__ Xb,
                                                 unsigned short* __restrict__ Yb) {
  __shared__ __attribute__((aligned(16))) short W1s[64 * 72];
  __shared__ __attribute__((aligned(16))) short W2s[64 * 72];
  int t = threadIdx.x;
  int w = t >> 6;
  int lane = t & 63;
  int col = lane & 15;
  int q = lane >> 4;
  int base_e = blockIdx.x * 64 + w * 16;

  // scatter this block's 64 edges: id tables + presence bits
  if (t < 64) {
    int e = blockIdx.x * 64 + t;
    int i = ei[e];
    int k = ei[NE + e];
    eid[i * NN + k] = e;
    eidT[k * NN + i] = e;
    atomicOr(&maskO[i * 16 + (k >> 5)], 1u << (k & 31));
    atomicOr(&maskI[k * 16 + (i >> 5)], 1u << (i & 31));
  }

  // stage W1,W2 (fp32 global -> bf16 LDS), 64 rows x 16 float4 granules
#pragma unroll
  for (int z = 0; z < 4; z++) {
    int gi = z * 256 + t;
    int r = gi >> 4, c = gi & 15;
    float4 v1 = ((const float4*)W1)[r * 16 + c];
    float4 v2 = ((const float4*)W2)[r * 16 + c];
    short4 s1, s2;
    s1.x = f2bf(v1.x); s1.y = f2bf(v1.y); s1.z = f2bf(v1.z); s1.w = f2bf(v1.w);
    s2.x = f2bf(v2.x); s2.y = f2bf(v2.y); s2.z = f2bf(v2.z); s2.w = f2bf(v2.w);
    *(short4*)(W1s + r * 72 + c * 4) = s1;
    *(short4*)(W2s + r * 72 + c * 4) = s2;
  }
  __syncthreads();

  // load C rows (fp32), convert to B-fragments
  short8_t bfrag[2];
#pragma unroll
  for (int ks = 0; ks < 2; ks++) {
    float4 c0 = ((const float4*)C)[(size_t)(base_e + col) * 16 + ks * 8 + q * 2];
    float4 c1 = ((const float4*)C)[(size_t)(base_e + col) * 16 + ks * 8 + q * 2 + 1];
    short8_t s;
    s[0] = (short)f2bf(c0.x); s[1] = (short)f2bf(c0.y);
    s[2] = (short)f2bf(c0.z); s[3] = (short)f2bf(c0.w);
    s[4] = (short)f2bf(c1.x); s[5] = (short)f2bf(c1.y);
    s[6] = (short)f2bf(c1.z); s[7] = (short)f2bf(c1.w);
    bfrag[ks] = s;
  }

  float4_t xa[4], ya[4];
#pragma unroll
  for (int ft = 0; ft < 4; ft++) {
    xa[ft] = (float4_t){0.f, 0.f, 0.f, 0.f};
    ya[ft] = (float4_t){0.f, 0.f, 0.f, 0.f};
  }
#pragma unroll
  for (int ks = 0; ks < 2; ks++) {
#pragma unroll
    for (int ft = 0; ft < 4; ft++) {
      short8_t a1 = *(const short8_t*)(W1s + (ft * 16 + col) * 72 + ks * 32 + q * 8);
      short8_t a2 = *(const short8_t*)(W2s + (ft * 16 + col) * 72 + ks * 32 + q * 8);
      xa[ft] = __builtin_amdgcn_mfma_f32_16x16x32_bf16(a1, bfrag[ks], xa[ft], 0, 0, 0);
      ya[ft] = __builtin_amdgcn_mfma_f32_16x16x32_bf16(a2, bfrag[ks], ya[ft], 0, 0, 0);
    }
  }
  // D[row=q*4+r -> f][col -> edge]; store bf16 short4
#pragma unroll
  for (int ft = 0; ft < 4; ft++) {
    short4 sx, sy;
    sx.x = (short)f2bf(xa[ft][0]); sx.y = (short)f2bf(xa[ft][1]);
    sx.z = (short)f2bf(xa[ft][2]); sx.w = (short)f2bf(xa[ft][3]);
    sy.x = (short)f2bf(ya[ft][0]); sy.y = (short)f2bf(ya[ft][1]);
    sy.z = (short)f2bf(ya[ft][2]); sy.w = (short)f2bf(ya[ft][3]);
    *(short4*)(Xb + (size_t)(base_e + col) * 64 + ft * 16 + q * 4) = sx;
    *(short4*)(Yb + (size_t)(base_e + col) * 64 + ft * 16 + q * 4) = sy;
  }
}

// ---------------------------------------------------------------------------
// K2: sparse product via bitmask intersection (one wave per edge, 4096 blocks
// -> 16 blocks/CU so gather latency is TLP-hidden), writes bf16 TM into
// tmpB[:,64:128].  First 96 blocks additionally convert W_mlp1/W_mlp2 to bf16
// (1 KB per block, consumed only by the later k_mlp2 launch).
// ---------------------------------------------------------------------------
__global__ __launch_bounds__(256) void k_spmm(const int* __restrict__ ei,
                                              const int* __restrict__ eid,
                                              const int* __restrict__ eidT,
                                              const unsigned* __restrict__ maskO,
                                              const unsigned* __restrict__ maskI,
                                              const unsigned short* __restrict__ Xb,
                                              const unsigned short* __restrict__ Yb,
                                              const float* __restrict__ Wm1,
                                              const float* __restrict__ Wm2,
                                              unsigned short* __restrict__ W1B,
                                              unsigned short* __restrict__ W2B,
                                              unsigned short* __restrict__ tmpB) {
  // W conversion side-job: 24576 float4 granules over the first 96 blocks
  if (blockIdx.x < 96) {
    int t4 = blockIdx.x * 256 + threadIdx.x;  // 0..24575
    if (t4 < 16384) {
      float4 v = ((const float4*)Wm1)[t4];
      short4 s;
      s.x = f2bf(v.x); s.y = f2bf(v.y); s.z = f2bf(v.z); s.w = f2bf(v.w);
      ((short4*)W1B)[t4] = s;
    } else {
      int i = t4 - 16384;
      float4 v = ((const float4*)Wm2)[i];
      short4 s;
      s.x = f2bf(v.x); s.y = f2bf(v.y); s.z = f2bf(v.z); s.w = f2bf(v.w);
      ((short4*)W2B)[i] = s;
    }
  }

  int lane = threadIdx.x & 63;
  int e = (blockIdx.x * 256 + threadIdx.x) >> 6;  // one wave per edge
  int i = ei[e];
  int k = ei[NE + e];
  unsigned mm = 0;
  if (lane < 16) mm = maskO[i * 16 + lane] & maskI[k * 16 + lane];
  unsigned long long has = __ballot(mm != 0);
  float acc = 0.f;
  while (has) {
    int l = (int)__builtin_ctzll(has);
    has &= has - 1;
    unsigned bits = __shfl(mm, l);
    while (bits) {
      int b = __builtin_ctz(bits);
      bits &= bits - 1;
      int j = l * 32 + b;
      int s1 = eid[i * NN + j];   // uniform address -> broadcast load
      int s2 = eidT[k * NN + j];
      float xv = bf2f(Xb[(size_t)s1 * 64 + lane]);
      float yv = bf2f(Yb[(size_t)s2 * 64 + lane]);
      acc = fmaf(xv, yv, acc);
    }
  }
  tmpB[(size_t)e * 128 + 64 + lane] = f2bf(acc);
}

// ---------------------------------------------------------------------------
// K3: C -> bf16 tmpB[:,0:64] is folded here as the first act of the MLP
// kernel?  No — kept in tmpB writer below (see k_cvtC) for occupancy reasons.
// (k_mlp2 unchanged from R5: block = 2 edge-groups x 2 hidden-halves,
// 512 blocks -> 8 waves/CU, W staged per 2x64-hid chunk, hS per-wave.)
// ---------------------------------------------------------------------------
__global__ __launch_bounds__(256) void k_mlp2(
    const float* __restrict__ C,              // [NE][64] fp32 (C half source)
    const unsigned short* __restrict__ tmpB,  // [NE][128] (TM half valid)
    const unsigned short* __restrict__ W1B,   // [512][128]
    const unsigned short* __restrict__ W2B,   // [64][512]
    float* __restrict__ out) {                // [NE][64]
  __shared__ __attribute__((aligned(16))) short W1s[128 * 136];  // 34816 B
  __shared__ __attribute__((aligned(16))) short W2s[64 * 136];   // 17408 B
  __shared__ __attribute__((aligned(16))) short hS[4][16 * 72];  //  9216 B

  int t = threadIdx.x;
  int w = t >> 6;
  int lane = t & 63;
  int col = lane & 15;
  int q = lane >> 4;
  int g = w & 1;
  int h = w >> 1;
  int base_e = blockIdx.x * 32 + g * 16;

  // B-fragments of [C | TM]: C half straight from fp32 global (convert in
  // flight — tmpB's C half is never written), TM half from tmpB.
  short8_t btmp[4];
#pragma unroll
  for (int ks = 0; ks < 2; ks++) {
    float4 c0 = ((const float4*)C)[(size_t)(base_e + col) * 16 + ks * 8 + q * 2];
    float4 c1 = ((const float4*)C)[(size_t)(base_e + col) * 16 + ks * 8 + q * 2 + 1];
    short8_t s;
    s[0] = (short)f2bf(c0.x); s[1] = (short)f2bf(c0.y);
    s[2] = (short)f2bf(c0.z); s[3] = (short)f2bf(c0.w);
    s[4] = (short)f2bf(c1.x); s[5] = (short)f2bf(c1.y);
    s[6] = (short)f2bf(c1.z); s[7] = (short)f2bf(c1.w);
    btmp[ks] = s;
  }
#pragma unroll
  for (int ks = 2; ks < 4; ks++)
    btmp[ks] = *(const short8_t*)(tmpB + (size_t)(base_e + col) * 128 + ks * 32 + q * 8);

  float4_t oacc[4];
#pragma unroll
  for (int ft = 0; ft < 4; ft++) oacc[ft] = (float4_t){0.f, 0.f, 0.f, 0.f};

  for (int it = 0; it < 4; it++) {
    __syncthreads();
    {  // stage W1 chunks (it) and (4+it): 128 rows x 16 uint4
      uint4* d1 = (uint4*)W1s;
      const uint4* s1 = (const uint4*)W1B;
#pragma unroll
      for (int z = 0; z < 8; z++) {
        int gi = z * 256 + t;
        int r = gi >> 4, c = gi & 15;
        int grow = ((r >> 6) * 4 + it) * 64 + (r & 63);
        d1[r * 17 + c] = s1[(size_t)grow * 16 + c];
      }
      uint4* d2 = (uint4*)W2s;
      const uint4* s2 = (const uint4*)W2B;
#pragma unroll
      for (int z = 0; z < 4; z++) {
        int gi = z * 256 + t;
        int r = gi >> 4, c = gi & 15;
        int gc = ((c >> 3) * 4 + it) * 8 + (c & 7);
        d2[r * 17 + c] = s2[(size_t)r * 64 + gc];
      }
    }
    __syncthreads();

    // GEMM1: hT[hid][edge] for this half's 64-hid chunk
#pragma unroll
    for (int ht = 0; ht < 4; ht++) {
      float4_t hacc = (float4_t){0.f, 0.f, 0.f, 0.f};
#pragma unroll
      for (int ks = 0; ks < 4; ks++) {
        short8_t af = *(const short8_t*)(W1s + (h * 64 + ht * 16 + col) * 136 + ks * 32 + q * 8);
        hacc = __builtin_amdgcn_mfma_f32_16x16x32_bf16(af, btmp[ks], hacc, 0, 0, 0);
      }
      short4 hp;  // regs r=0..3 -> hid ht*16+q*4+r, edge=col
      hp.x = (short)f2bf(fmaxf(hacc[0], 0.f));
      hp.y = (short)f2bf(fmaxf(hacc[1], 0.f));
      hp.z = (short)f2bf(fmaxf(hacc[2], 0.f));
      hp.w = (short)f2bf(fmaxf(hacc[3], 0.f));
      *(short4*)(&hS[w][col * 72 + ht * 16 + q * 4]) = hp;
    }
    // hS tile is per-wave: lgkmcnt-only hazard, no block barrier needed

    // GEMM2: oacc += relu(h) @ W2^T over this half's chunk
#pragma unroll
    for (int ks2 = 0; ks2 < 2; ks2++) {
      short8_t a2 = *(const short8_t*)(&hS[w][col * 72 + ks2 * 32 + q * 8]);
#pragma unroll
      for (int ft = 0; ft < 4; ft++) {
        short8_t b2 = *(const short8_t*)(W2s + (ft * 16 + col) * 136 + h * 64 + ks2 * 32 + q * 8);
        oacc[ft] = __builtin_amdgcn_mfma_f32_16x16x32_bf16(a2, b2, oacc[ft], 0, 0, 0);
      }
    }
  }

  __syncthreads();
  float* red = (float*)W1s;  // [32 edges][stride 66] fp32
  if (h == 1) {
#pragma unroll
    for (int ft = 0; ft < 4; ft++)
#pragma unroll
      for (int r = 0; r < 4; r++)
        red[(g * 16 + q * 4 + r) * 66 + ft * 16 + col] = oacc[ft][r];
  }
  __syncthreads();
  if (h == 0) {
#pragma unroll
    for (int ft = 0; ft < 4; ft++)
#pragma unroll
      for (int r = 0; r < 4; r++) {
        float v = oacc[ft][r] + red[(g * 16 + q * 4 + r) * 66 + ft * 16 + col];
        out[(size_t)(base_e + q * 4 + r) * 64 + ft * 16 + col] = v;
      }
  }
}

// ---------------------------------------------------------------------------
extern "C" void kernel_launch(void* const* d_in, const int* in_sizes, int n_in,
                              void* d_out, int out_size, void* d_ws, size_t ws_size,
                              hipStream_t stream) {
  const int* ei = (const int*)d_in[0];       // [2, E]
  const float* C = (const float*)d_in[1];    // [E, 64]
  const float* W1 = (const float*)d_in[3];   // [64, 64]
  const float* W2 = (const float*)d_in[4];   // [64, 64]
  const float* Wm1 = (const float*)d_in[5];  // [512, 128]
  const float* Wm2 = (const float*)d_in[6];  // [64, 512]
  float* out = (float*)d_out;                // [E, 64]

  char* p = (char*)d_ws;
  int* eid = (int*)p;                 p += (size_t)NN * NN * 4;
  int* eidT = (int*)p;                p += (size_t)NN * NN * 4;
  unsigned* masks = (unsigned*)p;     p += (size_t)16384 * 4;  // maskO|maskI
  unsigned short* Xb = (unsigned short*)p;    p += (size_t)NE * NF * 2;
  unsigned short* Yb = (unsigned short*)p;    p += (size_t)NE * NF * 2;
  unsigned short* tmpB = (unsigned short*)p;  p += (size_t)NE * 128 * 2;
  unsigned short* W1B = (unsigned short*)p;   p += (size_t)512 * 128 * 2;
  unsigned short* W2B = (unsigned short*)p;   p += (size_t)64 * 512 * 2;
  unsigned* maskO = masks;
  unsigned* maskI = masks + 8192;

  hipMemsetAsync(masks, 0, 16384 * sizeof(unsigned), stream);
  k_xy_mfma<<<NE / 64, 256, 0, stream>>>(C, W1, W2, ei, eid, eidT, maskO, maskI, Xb, Yb);
  k_spmm<<<(NE * 64) / 256, 256, 0, stream>>>(ei, eid, eidT, maskO, maskI, Xb, Yb,
                                              Wm1, Wm2, W1B, W2B, tmpB);
  k_mlp2<<<NE / 32, 256, 0, stream>>>(C, tmpB, W1B, W2B, out);
}